// Round 3
// baseline (304.667 us; speedup 1.0000x reference)
//
#include <hip/hip_runtime.h>
#include <hip/hip_fp8.h>

#define S_LEN 512
#define BATCH 256
#define L 128
#define PAD_ID 0
#define START_ID 1

typedef int    i32x8 __attribute__((ext_vector_type(8)));
typedef int    i32x4 __attribute__((ext_vector_type(4)));
typedef float  f32x4 __attribute__((ext_vector_type(4)));
typedef unsigned int   u32x4 __attribute__((ext_vector_type(4)));
typedef unsigned short u16x2 __attribute__((ext_vector_type(2)));

__device__ __forceinline__ unsigned int umax2(unsigned int a, unsigned int b) {
    u16x2 x = __builtin_bit_cast(u16x2, a), y = __builtin_bit_cast(u16x2, b);
#if defined(__has_builtin) && __has_builtin(__builtin_elementwise_max)
    return __builtin_bit_cast(unsigned int, __builtin_elementwise_max(x, y));  // v_pk_max_u16
#else
    u16x2 r; r.x = x.x > y.x ? x.x : y.x; r.y = x.y > y.y ? x.y : y.y;
    return __builtin_bit_cast(unsigned int, r);
#endif
}
// NaN-killing sanitizer (fmaxf(NaN,lo)=lo on AMD): result always in [lo,hi], never NaN.
__device__ __forceinline__ float sane(float x, float lo, float hi) {
    return fminf(fmaxf(x, lo), hi);
}
// pack 4 f32 -> 4 fp8 e4m3 bytes in one dword (2 cvt_pk: lo half then hi half via opsel)
__device__ __forceinline__ int pk4(float a, float b, float c, float d) {
#if defined(__has_builtin) && __has_builtin(__builtin_amdgcn_cvt_pk_fp8_f32)
    int lo = __builtin_amdgcn_cvt_pk_fp8_f32(a, b, 0, false);
    return __builtin_amdgcn_cvt_pk_fp8_f32(c, d, lo, true);
#else
    __hip_fp8_e4m3 A(a), B(b), C(c), D(d);
    return (int)A.__x | ((int)B.__x << 8) | ((int)C.__x << 16) | ((int)D.__x << 24);
#endif
}
// exact max byte (u8) over 8 dwords of positive-e4m3 bytes, via even/odd u16 lanes
__device__ __forceinline__ unsigned int bmax8(u32x4 a, u32x4 b) {
    const unsigned int M = 0x00FF00FFu;
    unsigned int l0 = umax2(a.x & M, a.y & M), l1 = umax2(a.z & M, a.w & M);
    unsigned int l2 = umax2(b.x & M, b.y & M), l3 = umax2(b.z & M, b.w & M);
    unsigned int h0 = umax2((a.x >> 8) & M, (a.y >> 8) & M);
    unsigned int h1 = umax2((a.z >> 8) & M, (a.w >> 8) & M);
    unsigned int h2 = umax2((b.x >> 8) & M, (b.y >> 8) & M);
    unsigned int h3 = umax2((b.z >> 8) & M, (b.w >> 8) & M);
    unsigned int v = umax2(umax2(umax2(l0, l1), umax2(l2, l3)),
                           umax2(umax2(h0, h1), umax2(h2, h3)));
    u16x2 t = __builtin_bit_cast(u16x2, v);
    return (unsigned int)(t.x > t.y ? t.x : t.y);
}
__device__ __forceinline__ float fp8dec(unsigned int bb) {   // e4m3 byte -> float
    bb &= 0x7Fu;
    int e = (int)(bb >> 3), mt = (int)(bb & 7u);
    float v = e ? __builtin_ldexpf((float)(8 + mt), e - 10)
                : __builtin_ldexpf((float)mt, -9);
    return sane(v, 1e-9f, 448.f);
}
__device__ __forceinline__ f32x4 vexp4(f32x4 x) {
    f32x4 r;
    r.x = __expf(x.x); r.y = __expf(x.y); r.z = __expf(x.z); r.w = __expf(x.w);
    return r;
}
__device__ __forceinline__ f32x4 vmin4(f32x4 a, float c) {
    f32x4 r;
    r.x = fminf(a.x, c); r.y = fminf(a.y, c); r.z = fminf(a.z, c); r.w = fminf(a.w, c);
    return r;
}

// ws layout (unchanged): qf[256][128] fp8 | qb[256][128] fp8 | Sf[256] f32 | Sb[256] f32 | n[256] i32
#define WS_QF 0
#define WS_QB 32768
#define WS_SF 65536
#define WS_SB 66560
#define WS_N  67584

// prefix-ones length of row b, with byte/f32 mask-encoding self-detect (first 8KB scan).
__device__ __forceinline__ int compute_len(const void* masks, int b, int lane) {
    const unsigned int* mw0 = (const unsigned int*)masks;
    int pred = 0;
    #pragma unroll
    for (int k = 0; k < 32; ++k) {
        unsigned int w0 = mw0[lane + 64 * k];
        pred |= (w0 > 1u && w0 != 0x3f800000u);
    }
    const bool isbyte = (__ballot(pred) != 0ull);
    int cnt = 0;
    if (isbyte) {
        const unsigned int* mw = mw0 + b * (S_LEN / 4);
        #pragma unroll
        for (int k = 0; k < 2; ++k) {
            unsigned int w0 = mw[lane + 64 * k];
            cnt += ((w0 & 0xffu) != 0) + ((w0 & 0xff00u) != 0) +
                   ((w0 & 0xff0000u) != 0) + ((w0 & 0xff000000u) != 0);
        }
    } else {
        const unsigned int* mw = mw0 + b * S_LEN;
        #pragma unroll
        for (int k = 0; k < 8; ++k) cnt += (mw[lane + 64 * k] != 0u);
    }
    #pragma unroll
    for (int off = 32; off; off >>= 1) cnt += __shfl_xor(cnt, off, 64);
    return cnt;
}

// r14 (resubmit — r2 bench was an infra failure, no kernel verdict).
// Register-only step. r13 (passed -> layout HW-verified) proved: with B=state
// byte-replicated across the 16 m-lanes, every D column is identical, so lane (g,m)
// holds ALL 32 outputs y[16t+4g+r] in d_t[r]; and its next B-frag byte sl=4d+y
// needs exactly d_{sl&7}[sl>>3]. So the select tree + LDS round-trip are dead
// weight: repack reg->reg (16 cvt_pk via opsel). m-replication is inductive (all
// update inputs m-invariant). Rescale is exponent-only: kk = 2^(7-e) (bitcast),
// Se += e-7 integer; Sf = S_base + Se*ln2 (any uniform tracked scale is valid).
// Emit prefetch distance 3 (3x8 f32x4) covers L3/HBM latency.
// Blocks 0..511: scan (b=bid&255, dir=bid>>8). Blocks 512..767: gold.
__global__ __launch_bounds__(64, 1) void k_scan(
        const float* __restrict__ emit, const int* __restrict__ labels,
        const void* __restrict__ masks, const float* __restrict__ T,
        unsigned char* __restrict__ ws, float* __restrict__ out) {
    const int bid  = blockIdx.x;
    const int lane = threadIdx.x;

    if (bid >= 2 * BATCH) {               // ---- gold (exact f32) ----
        const int b = bid - 2 * BATCH;
        const int len = compute_len(masks, b, lane);
        float gsum = 0.f;
        for (int tt = lane; tt < len; tt += 64) {
            int nxt = labels[b * S_LEN + tt];
            int prv = tt ? labels[b * S_LEN + tt - 1] : START_ID;
            gsum += emit[((size_t)tt * BATCH + b) * L + nxt] + T[prv * L + nxt];
            if (tt == len - 1) gsum += T[nxt * L + PAD_ID];
        }
        #pragma unroll
        for (int off = 32; off; off >>= 1) gsum += __shfl_xor(gsum, off, 64);
        if (lane == 0) atomicAdd(out, -gsum);
        return;
    }

    const int b   = bid & (BATCH - 1);
    const int dir = bid >> 8;             // 0 = forward, 1 = backward
    const int g = lane >> 4, m = lane & 15;

    const int len = compute_len(masks, b, lane);
    const int n  = len - 1;
    const int kf = n / 2;
    const int nB = n - kf - 1;
    const int steps = dir ? (nB > 0 ? nB : 0) : kf;
    if (dir == 1 && n < 1) return;        // inactive backward chain

    // ---- A-fragments: E rows in f8f6f4 swizzled layout (row = m, byte->k) ----
    // fwd: A_t[m][k] = exp(T[k][16t+m])   (y[j] = sum_i expT[i][j] q[i])
    // bwd: A_t[m][k] = exp(T[16t+m][k])   (y[j] = sum_i expT[j][i] u[i])
    i32x8 Af[8];
    #pragma unroll
    for (int t = 0; t < 8; ++t) {
        #pragma unroll
        for (int d = 0; d < 8; ++d) {
            float v[4];
            #pragma unroll
            for (int y = 0; y < 4; ++y) {
                int sl = 4 * d + y;
                int k  = 16 * (sl & 7) + 4 * g + (sl >> 3);
                int idx = dir ? ((16 * t + m) * L + k) : (k * L + 16 * t + m);
                v[y] = __expf(T[idx]);
            }
            Af[t][d] = pk4(v[0], v[1], v[2], v[3]);
        }
    }

    // ---- init state q0 entirely in registers ----
    // fwd: f[k] = emit[0][b][k] + T[START][k]; bwd: f[k] = emit[n][b][k] + T[k][PAD]
    float S_base;
    i32x8 Aq;
    {
        f32x4 fv[8];
        const float* e0 = emit + (dir ? ((size_t)n * BATCH + b) * L : (size_t)b * L);
        #pragma unroll
        for (int t = 0; t < 8; ++t) {
            int k0 = 16 * t + 4 * g;
            f32x4 ev4 = *(const f32x4*)(e0 + k0);
            f32x4 tv;
            if (dir == 0) {
                tv = *(const f32x4*)(T + START_ID * L + k0);
            } else {
                tv.x = T[(k0 + 0) * L + PAD_ID];
                tv.y = T[(k0 + 1) * L + PAD_ID];
                tv.z = T[(k0 + 2) * L + PAD_ID];
                tv.w = T[(k0 + 3) * L + PAD_ID];
            }
            fv[t] = ev4 + tv;
        }
        float mx = -1e30f;
        #pragma unroll
        for (int t = 0; t < 8; ++t)
            mx = fmaxf(mx, fmaxf(fmaxf(fv[t].x, fv[t].y), fmaxf(fv[t].z, fv[t].w)));
        // values m-replicated; only the 4 g-groups differ
        mx = fmaxf(mx, __shfl_xor(mx, 16, 64));
        mx = fmaxf(mx, __shfl_xor(mx, 32, 64));
        S_base = mx;
        f32x4 pv[8];
        #pragma unroll
        for (int t = 0; t < 8; ++t) pv[t] = vexp4(fv[t] - S_base);
        Aq[0] = pk4(pv[0].x, pv[1].x, pv[2].x, pv[3].x);
        Aq[1] = pk4(pv[4].x, pv[5].x, pv[6].x, pv[7].x);
        Aq[2] = pk4(pv[0].y, pv[1].y, pv[2].y, pv[3].y);
        Aq[3] = pk4(pv[4].y, pv[5].y, pv[6].y, pv[7].y);
        Aq[4] = pk4(pv[0].z, pv[1].z, pv[2].z, pv[3].z);
        Aq[5] = pk4(pv[4].z, pv[5].z, pv[6].z, pv[7].z);
        Aq[6] = pk4(pv[0].w, pv[1].w, pv[2].w, pv[3].w);
        Aq[7] = pk4(pv[4].w, pv[5].w, pv[6].w, pv[7].w);
    }

    // ---- hot loop: zero LDS, zero cross-lane (except 2 shfl for the scale hint) ----
    int Se = 0;
    const f32x4 z = {0.f, 0.f, 0.f, 0.f};

    if (steps > 0) {
        auto ldrow8 = [&](int idx, f32x4* dst) {
            int ii  = idx < steps ? idx : steps - 1;   // clamp overshoot
            int row = dir ? (n - 1 - ii) : (1 + ii);
            const float* ep = emit + ((size_t)row * BATCH + b) * L + 4 * g;
            #pragma unroll
            for (int t = 0; t < 8; ++t) dst[t] = *(const f32x4*)(ep + 16 * t);
        };
        f32x4 ea[8], eb[8], ec[8];
        ldrow8(0, ea); ldrow8(1, eb); ldrow8(2, ec);
        int i = 0;

#define MFS(AT) __builtin_amdgcn_mfma_scale_f32_16x16x128_f8f6f4((AT), Aq, z, 0, 0, 0, 127, 0, 127)
#define STEP(EB)                                                                   \
        {                                                                          \
            f32x4 d0 = MFS(Af[0]), d1 = MFS(Af[1]), d2 = MFS(Af[2]), d3 = MFS(Af[3]); \
            f32x4 d4 = MFS(Af[4]), d5 = MFS(Af[5]), d6 = MFS(Af[6]), d7 = MFS(Af[7]); \
            f32x4 x0 = vexp4(EB[0]), x1 = vexp4(EB[1]), x2 = vexp4(EB[2]),         \
                  x3 = vexp4(EB[3]), x4 = vexp4(EB[4]), x5 = vexp4(EB[5]),         \
                  x6 = vexp4(EB[6]), x7 = vexp4(EB[7]);                            \
            u32x4 qlo = {(unsigned)Aq[0], (unsigned)Aq[1],                         \
                         (unsigned)Aq[2], (unsigned)Aq[3]};                        \
            u32x4 qhi = {(unsigned)Aq[4], (unsigned)Aq[5],                         \
                         (unsigned)Aq[6], (unsigned)Aq[7]};                        \
            unsigned int qm = bmax8(qlo, qhi);                                     \
            {                                                                      \
                unsigned int q2 = (unsigned int)__shfl_xor((int)qm, 16, 64);       \
                qm = qm > q2 ? qm : q2;                                            \
                q2 = (unsigned int)__shfl_xor((int)qm, 32, 64);                    \
                qm = qm > q2 ? qm : q2;                                            \
            }                                                                      \
            int e7 = (int)(qm >> 3) - 7;                                           \
            Se += e7;                                                              \
            float kk = __builtin_bit_cast(float, (unsigned int)(127 - e7) << 23);  \
            x0 *= kk; x1 *= kk; x2 *= kk; x3 *= kk;                                \
            x4 *= kk; x5 *= kk; x6 *= kk; x7 *= kk;                                \
            f32x4 p0 = vmin4(d0 * x0, 448.f), p1 = vmin4(d1 * x1, 448.f);          \
            f32x4 p2 = vmin4(d2 * x2, 448.f), p3 = vmin4(d3 * x3, 448.f);          \
            f32x4 p4 = vmin4(d4 * x4, 448.f), p5 = vmin4(d5 * x5, 448.f);          \
            f32x4 p6 = vmin4(d6 * x6, 448.f), p7 = vmin4(d7 * x7, 448.f);          \
            Aq[0] = pk4(p0.x, p1.x, p2.x, p3.x);                                   \
            Aq[1] = pk4(p4.x, p5.x, p6.x, p7.x);                                   \
            Aq[2] = pk4(p0.y, p1.y, p2.y, p3.y);                                   \
            Aq[3] = pk4(p4.y, p5.y, p6.y, p7.y);                                   \
            Aq[4] = pk4(p0.z, p1.z, p2.z, p3.z);                                   \
            Aq[5] = pk4(p4.z, p5.z, p6.z, p7.z);                                   \
            Aq[6] = pk4(p0.w, p1.w, p2.w, p3.w);                                   \
            Aq[7] = pk4(p4.w, p5.w, p6.w, p7.w);                                   \
        }

        for (;;) {
            STEP(ea); if (++i == steps) break; ldrow8(i + 2, ea);
            STEP(eb); if (++i == steps) break; ldrow8(i + 2, eb);
            STEP(ec); if (++i == steps) break; ldrow8(i + 2, ec);
        }
#undef STEP
#undef MFS
    }

    // ---- seam + scale to ws (byte order identical to r12/r13: slot s holds q[k(s)]) ----
    if (m == 0) {
        i32x4* sp = (i32x4*)(ws + (dir ? WS_QB : WS_QF) + b * L + 32 * g);
        sp[0] = (i32x4){Aq[0], Aq[1], Aq[2], Aq[3]};
        sp[1] = (i32x4){Aq[4], Aq[5], Aq[6], Aq[7]};
    }
    if (lane == 0) {
        ((float*)(ws + (dir ? WS_SB : WS_SF)))[b] = S_base + 0.69314718f * (float)Se;
        if (dir == 0) ((int*)(ws + WS_N))[b] = n;
    }
}

// Exact-f32 join: enc_b = Sf + Sb + log(q_kf^T E u_{kf+1})  (n=0: Sf + log(q0.expTpad))
__global__ __launch_bounds__(64, 1) void k_join(
        const float* __restrict__ T, const unsigned char* __restrict__ ws,
        float* __restrict__ out) {
    const int b = blockIdx.x;
    const int lane = threadIdx.x;
    __shared__ float qsh[L], ush[L];

    const int n = ((const int*)(ws + WS_N))[b];
    // decode seam bytes (store-order slot s -> label 16*(s&7)+(s>>3))
    #pragma unroll
    for (int k = 0; k < 2; ++k) {
        int s = lane + 64 * k;
        int j = 16 * (s & 7) + (s >> 3);
        qsh[j] = fp8dec(ws[WS_QF + b * L + s]);
        ush[j] = fp8dec(ws[WS_QB + b * L + s]);
    }
    __syncthreads();

    float ev = 0.f;
    if (n >= 1) {
        #pragma unroll
        for (int k = 0; k < 2; ++k) {
            int j = lane + 64 * k;
            float v0 = 0.f, v1 = 0.f, v2 = 0.f, v3 = 0.f;
            #pragma unroll 8
            for (int i = 0; i < L; i += 4) {
                v0 = fmaf(qsh[i + 0], __expf(T[(i + 0) * L + j]), v0);
                v1 = fmaf(qsh[i + 1], __expf(T[(i + 1) * L + j]), v1);
                v2 = fmaf(qsh[i + 2], __expf(T[(i + 2) * L + j]), v2);
                v3 = fmaf(qsh[i + 3], __expf(T[(i + 3) * L + j]), v3);
            }
            ev += ((v0 + v1) + (v2 + v3)) * ush[j];
        }
    } else {
        #pragma unroll
        for (int k = 0; k < 2; ++k) {
            int j = lane + 64 * k;
            ev += qsh[j] * __expf(T[j * L + PAD_ID]);
        }
    }
    #pragma unroll
    for (int off = 32; off; off >>= 1) ev += __shfl_xor(ev, off, 64);

    if (lane == 0) {
        float Sf = ((const float*)(ws + WS_SF))[b];
        float Sb = (n >= 1) ? ((const float*)(ws + WS_SB))[b] : 0.f;
        float enc = Sf + Sb + __logf(fmaxf(ev, 1e-35f));
        atomicAdd(out, sane(enc, -1e30f, 1e30f));
    }
}

extern "C" void kernel_launch(void* const* d_in, const int* in_sizes, int n_in,
                              void* d_out, int out_size, void* d_ws, size_t ws_size,
                              hipStream_t stream) {
    const float* emit   = (const float*)d_in[0];
    const int*   labels = (const int*)d_in[1];
    const void*  masks  = d_in[2];
    const float* T      = (const float*)d_in[3];
    float* out = (float*)d_out;
    unsigned char* ws = (unsigned char*)d_ws;

    hipMemsetAsync(d_out, 0, sizeof(float), stream);
    k_scan<<<dim3(3 * BATCH), dim3(64), 0, stream>>>(emit, labels, masks, T, ws, out);
    k_join<<<dim3(BATCH),     dim3(64), 0, stream>>>(T, ws, out);
}

// Round 17
// 275.563 us; speedup vs baseline: 1.1056x; 1.1056x over previous
//
#include <hip/hip_runtime.h>
#include <hip/hip_fp8.h>

#define S_LEN 512
#define BATCH 256
#define L 128
#define PAD_ID 0
#define START_ID 1

typedef int    i32x8 __attribute__((ext_vector_type(8)));
typedef int    i32x4 __attribute__((ext_vector_type(4)));
typedef float  f32x4 __attribute__((ext_vector_type(4)));
typedef unsigned int   u32x4 __attribute__((ext_vector_type(4)));
typedef unsigned short u16x2 __attribute__((ext_vector_type(2)));

__device__ __forceinline__ unsigned int umax2(unsigned int a, unsigned int b) {
    u16x2 x = __builtin_bit_cast(u16x2, a), y = __builtin_bit_cast(u16x2, b);
#if defined(__has_builtin) && __has_builtin(__builtin_elementwise_max)
    return __builtin_bit_cast(unsigned int, __builtin_elementwise_max(x, y));  // v_pk_max_u16
#else
    u16x2 r; r.x = x.x > y.x ? x.x : y.x; r.y = x.y > y.y ? x.y : y.y;
    return __builtin_bit_cast(unsigned int, r);
#endif
}
// NaN-killing sanitizer (fmaxf(NaN,lo)=lo on AMD): result always in [lo,hi], never NaN.
__device__ __forceinline__ float sane(float x, float lo, float hi) {
    return fminf(fmaxf(x, lo), hi);
}
__device__ __forceinline__ unsigned short f2bf(float f) {   // RNE f32->bf16
    unsigned int u = __builtin_bit_cast(unsigned int, f);
    return (unsigned short)((u + 0x7fffu + ((u >> 16) & 1u)) >> 16);
}
// pack 4 f32 -> 4 fp8 e4m3 bytes in one dword (2 cvt_pk: lo half then hi half via opsel)
__device__ __forceinline__ int pk4(float a, float b, float c, float d) {
#if defined(__has_builtin) && __has_builtin(__builtin_amdgcn_cvt_pk_fp8_f32)
    int lo = __builtin_amdgcn_cvt_pk_fp8_f32(a, b, 0, false);
    return __builtin_amdgcn_cvt_pk_fp8_f32(c, d, lo, true);
#else
    __hip_fp8_e4m3 A(a), B(b), C(c), D(d);
    return (int)A.__x | ((int)B.__x << 8) | ((int)C.__x << 16) | ((int)D.__x << 24);
#endif
}
// exact max byte (u8) over 8 dwords of positive-e4m3 bytes, via even/odd u16 lanes
__device__ __forceinline__ unsigned int bmax8(u32x4 a, u32x4 b) {
    const unsigned int M = 0x00FF00FFu;
    unsigned int l0 = umax2(a.x & M, a.y & M), l1 = umax2(a.z & M, a.w & M);
    unsigned int l2 = umax2(b.x & M, b.y & M), l3 = umax2(b.z & M, b.w & M);
    unsigned int h0 = umax2((a.x >> 8) & M, (a.y >> 8) & M);
    unsigned int h1 = umax2((a.z >> 8) & M, (a.w >> 8) & M);
    unsigned int h2 = umax2((b.x >> 8) & M, (b.y >> 8) & M);
    unsigned int h3 = umax2((b.z >> 8) & M, (b.w >> 8) & M);
    unsigned int v = umax2(umax2(umax2(l0, l1), umax2(l2, l3)),
                           umax2(umax2(h0, h1), umax2(h2, h3)));
    u16x2 t = __builtin_bit_cast(u16x2, v);
    return (unsigned int)(t.x > t.y ? t.x : t.y);
}
__device__ __forceinline__ float fp8dec(unsigned int bb) {   // e4m3 byte -> float
    bb &= 0x7Fu;
    int e = (int)(bb >> 3), mt = (int)(bb & 7u);
    float v = e ? __builtin_ldexpf((float)(8 + mt), e - 10)
                : __builtin_ldexpf((float)mt, -9);
    return sane(v, 1e-9f, 448.f);
}
__device__ __forceinline__ f32x4 vexp4(f32x4 x) {
    f32x4 r;
    r.x = __expf(x.x); r.y = __expf(x.y); r.z = __expf(x.z); r.w = __expf(x.w);
    return r;
}
__device__ __forceinline__ f32x4 vmin4(f32x4 a, float c) {
    f32x4 r;
    r.x = fminf(a.x, c); r.y = fminf(a.y, c); r.z = fminf(a.z, c); r.w = fminf(a.w, c);
    return r;
}
// two bf16-pair dwords (+packed exponent adjust) -> f32x4 {lo0,hi0,lo1,hi1}
__device__ __forceinline__ f32x4 xpair(int w0, int w1, u16x2 adj) {
    u16x2 a = __builtin_bit_cast(u16x2, w0) - adj;   // v_pk_sub_u16: exponent -= e7
    u16x2 c = __builtin_bit_cast(u16x2, w1) - adj;
    unsigned ua = __builtin_bit_cast(unsigned, a), uc = __builtin_bit_cast(unsigned, c);
    f32x4 r;
    r.x = __builtin_bit_cast(float, ua << 16);
    r.y = __builtin_bit_cast(float, ua & 0xffff0000u);
    r.z = __builtin_bit_cast(float, uc << 16);
    r.w = __builtin_bit_cast(float, uc & 0xffff0000u);
    return r;
}

// ws layout: qf[256][128] fp8 | qb[256][128] fp8 | Sf[256] f32 | Sb[256] f32 | n[256] i32 | exp-table bf16
#define WS_QF 0
#define WS_QB 32768
#define WS_SF 65536
#define WS_SB 66560
#define WS_N  67584
#define WS_TAB 68864                                    // 256-aligned, after n[256]
#define TAB_BYTES ((size_t)S_LEN * BATCH * L * 2)       // 33,554,432

// prefix-ones length of row b, with byte/f32 mask-encoding self-detect (first 8KB scan).
__device__ __forceinline__ int compute_len(const void* masks, int b, int lane) {
    const unsigned int* mw0 = (const unsigned int*)masks;
    int pred = 0;
    #pragma unroll
    for (int k = 0; k < 32; ++k) {
        unsigned int w0 = mw0[lane + 64 * k];
        pred |= (w0 > 1u && w0 != 0x3f800000u);
    }
    const bool isbyte = (__ballot(pred) != 0ull);
    int cnt = 0;
    if (isbyte) {
        const unsigned int* mw = mw0 + b * (S_LEN / 4);
        #pragma unroll
        for (int k = 0; k < 2; ++k) {
            unsigned int w0 = mw[lane + 64 * k];
            cnt += ((w0 & 0xffu) != 0) + ((w0 & 0xff00u) != 0) +
                   ((w0 & 0xff0000u) != 0) + ((w0 & 0xff000000u) != 0);
        }
    } else {
        const unsigned int* mw = mw0 + b * S_LEN;
        #pragma unroll
        for (int k = 0; k < 8; ++k) cnt += (mw[lane + 64 * k] != 0u);
    }
    #pragma unroll
    for (int off = 32; off; off >>= 1) cnt += __shfl_xor(cnt, off, 64);
    return cnt;
}

__device__ __forceinline__ void gold_block(
        const float* __restrict__ emit, const int* __restrict__ labels,
        const void* __restrict__ masks, const float* __restrict__ T,
        float* __restrict__ out, int b, int lane) {
    const int len = compute_len(masks, b, lane);
    float gsum = 0.f;
    for (int tt = lane; tt < len; tt += 64) {
        int nxt = labels[b * S_LEN + tt];
        int prv = tt ? labels[b * S_LEN + tt - 1] : START_ID;
        gsum += emit[((size_t)tt * BATCH + b) * L + nxt] + T[prv * L + nxt];
        if (tt == len - 1) gsum += T[nxt * L + PAD_ID];
    }
    #pragma unroll
    for (int off = 32; off; off >>= 1) gsum += __shfl_xor(gsum, off, 64);
    if (lane == 0) atomicAdd(out, -gsum);
}

// ---- pre-pass: tab[(row*256+b)*4+g][t][y] = bf16(exp(emit[row][b][16t+4g+y])) ----
// Lane-swizzled so each scan lane's 32 values are one contiguous 64B block.
__global__ __launch_bounds__(256, 4) void k_pre(
        const float* __restrict__ emit, unsigned char* __restrict__ tab) {
    const int N4 = S_LEN * BATCH * 32;                 // dword-pair units
    int o = blockIdx.x * 256 + threadIdx.x;
    const int stride = gridDim.x * 256;
    for (; o < N4; o += stride) {
        int base = o >> 5, t = o & 7, g = (o >> 3) & 3;
        f32x4 v = *(const f32x4*)(emit + ((size_t)base << 7) + 16 * t + 4 * g);
        f32x4 e = vexp4(v);
        unsigned d0 = (unsigned)f2bf(e.x) | ((unsigned)f2bf(e.y) << 16);
        unsigned d1 = (unsigned)f2bf(e.z) | ((unsigned)f2bf(e.w) << 16);
        uint2 pr; pr.x = d0; pr.y = d1;
        *(uint2*)(tab + (size_t)o * 8) = pr;
    }
}

// r15b (resubmit — r13..r16 benches were infra failures; the r12 paste bug
// fix is in). LOADT/STEPT take the four named buffer registers as explicit
// parameters — no token pasting. Semantics identical to the audited r15:
// (1) r14's pointer-lambda prefetch arrays were NOT SROA'd (VGPR=168 << live set
//     ~230) -> scratch round-trip per step. Now: NAMED i32x4 buffers, static
//     indices only.
// (2) 32 v_exp_f32 (quarter-rate trans) per step -> pre-pass table of bf16
//     exp(emit) in lane-order; per-step unpack is full-rate shl/and, and the
//     2^-e7 rescale folds into the bf16 exponent via 16 v_pk_sub_u16.
// Layout facts (HW-verified r13): byte sl=4d+y of the B-frag needs d_{sl&7}[sl>>3];
// m-replication of state is inductive. Blocks 0..511: scan; 512..767: gold.
__global__ __launch_bounds__(64, 1) void k_scan_tab(
        const float* __restrict__ emit, const int* __restrict__ labels,
        const void* __restrict__ masks, const float* __restrict__ T,
        unsigned char* __restrict__ ws, float* __restrict__ out) {
    const int bid  = blockIdx.x;
    const int lane = threadIdx.x;

    if (bid >= 2 * BATCH) { gold_block(emit, labels, masks, T, out, bid - 2 * BATCH, lane); return; }

    const int b   = bid & (BATCH - 1);
    const int dir = bid >> 8;             // 0 = forward, 1 = backward
    const int g = lane >> 4, m = lane & 15;

    const int len = compute_len(masks, b, lane);
    const int n  = len - 1;
    const int kf = n / 2;
    const int nB = n - kf - 1;
    const int steps = dir ? (nB > 0 ? nB : 0) : kf;
    if (dir == 1 && n < 1) return;        // inactive backward chain

    // ---- A-fragments: E rows in f8f6f4 swizzled layout (row = m, byte->k) ----
    i32x8 Af[8];
    #pragma unroll
    for (int t = 0; t < 8; ++t) {
        #pragma unroll
        for (int d = 0; d < 8; ++d) {
            float v[4];
            #pragma unroll
            for (int y = 0; y < 4; ++y) {
                int sl = 4 * d + y;
                int k  = 16 * (sl & 7) + 4 * g + (sl >> 3);
                int idx = dir ? ((16 * t + m) * L + k) : (k * L + 16 * t + m);
                v[y] = __expf(T[idx]);
            }
            Af[t][d] = pk4(v[0], v[1], v[2], v[3]);
        }
    }

    // ---- init state q0 entirely in registers (identical to r14, verified) ----
    float S_base;
    i32x8 Aq;
    {
        f32x4 fv[8];
        const float* e0 = emit + (dir ? ((size_t)n * BATCH + b) * L : (size_t)b * L);
        #pragma unroll
        for (int t = 0; t < 8; ++t) {
            int k0 = 16 * t + 4 * g;
            f32x4 ev4 = *(const f32x4*)(e0 + k0);
            f32x4 tv;
            if (dir == 0) {
                tv = *(const f32x4*)(T + START_ID * L + k0);
            } else {
                tv.x = T[(k0 + 0) * L + PAD_ID];
                tv.y = T[(k0 + 1) * L + PAD_ID];
                tv.z = T[(k0 + 2) * L + PAD_ID];
                tv.w = T[(k0 + 3) * L + PAD_ID];
            }
            fv[t] = ev4 + tv;
        }
        float mx = -1e30f;
        #pragma unroll
        for (int t = 0; t < 8; ++t)
            mx = fmaxf(mx, fmaxf(fmaxf(fv[t].x, fv[t].y), fmaxf(fv[t].z, fv[t].w)));
        mx = fmaxf(mx, __shfl_xor(mx, 16, 64));
        mx = fmaxf(mx, __shfl_xor(mx, 32, 64));
        S_base = mx;
        f32x4 pv[8];
        #pragma unroll
        for (int t = 0; t < 8; ++t) pv[t] = vexp4(fv[t] - S_base);
        Aq[0] = pk4(pv[0].x, pv[1].x, pv[2].x, pv[3].x);
        Aq[1] = pk4(pv[4].x, pv[5].x, pv[6].x, pv[7].x);
        Aq[2] = pk4(pv[0].y, pv[1].y, pv[2].y, pv[3].y);
        Aq[3] = pk4(pv[4].y, pv[5].y, pv[6].y, pv[7].y);
        Aq[4] = pk4(pv[0].z, pv[1].z, pv[2].z, pv[3].z);
        Aq[5] = pk4(pv[4].z, pv[5].z, pv[6].z, pv[7].z);
        Aq[6] = pk4(pv[0].w, pv[1].w, pv[2].w, pv[3].w);
        Aq[7] = pk4(pv[4].w, pv[5].w, pv[6].w, pv[7].w);
    }

    // ---- hot loop: named double-buffer regs, bf16 table, no trans ops ----
    int Se = 0;
    const f32x4 z = {0.f, 0.f, 0.f, 0.f};
    const unsigned char* tab = ws + WS_TAB;

    if (steps > 0) {
        i32x4 wA0, wA1, wA2, wA3, wB0, wB1, wB2, wB3;

#define LOADT(W0, W1, W2, W3, idx)                                                 \
        {                                                                          \
            int ii  = (idx) < steps ? (idx) : steps - 1;                           \
            int row = dir ? (n - 1 - ii) : (1 + ii);                               \
            const i32x4* tp = (const i32x4*)(tab +                                 \
                (((size_t)(row * BATCH + b)) << 8) + (g << 6));                    \
            W0 = tp[0]; W1 = tp[1]; W2 = tp[2]; W3 = tp[3];                        \
        }

#define MFS(AT) __builtin_amdgcn_mfma_scale_f32_16x16x128_f8f6f4((AT), Aq, z, 0, 0, 0, 127, 0, 127)
#define STEPT(W0, W1, W2, W3)                                                      \
        {                                                                          \
            f32x4 d0 = MFS(Af[0]), d1 = MFS(Af[1]), d2 = MFS(Af[2]), d3 = MFS(Af[3]); \
            f32x4 d4 = MFS(Af[4]), d5 = MFS(Af[5]), d6 = MFS(Af[6]), d7 = MFS(Af[7]); \
            u32x4 qlo = {(unsigned)Aq[0], (unsigned)Aq[1],                         \
                         (unsigned)Aq[2], (unsigned)Aq[3]};                        \
            u32x4 qhi = {(unsigned)Aq[4], (unsigned)Aq[5],                         \
                         (unsigned)Aq[6], (unsigned)Aq[7]};                        \
            unsigned int qm = bmax8(qlo, qhi);                                     \
            {                                                                      \
                unsigned int q2 = (unsigned int)__shfl_xor((int)qm, 16, 64);       \
                qm = qm > q2 ? qm : q2;                                            \
                q2 = (unsigned int)__shfl_xor((int)qm, 32, 64);                    \
                qm = qm > q2 ? qm : q2;                                            \
            }                                                                      \
            int e7 = (int)(qm >> 3) - 7;                                           \
            Se += e7;                                                              \
            unsigned short as = (unsigned short)(e7 << 7);                         \
            u16x2 adj; adj.x = as; adj.y = as;                                     \
            f32x4 x0 = xpair((W0).x, (W0).y, adj);                                 \
            f32x4 x1 = xpair((W0).z, (W0).w, adj);                                 \
            f32x4 x2 = xpair((W1).x, (W1).y, adj);                                 \
            f32x4 x3 = xpair((W1).z, (W1).w, adj);                                 \
            f32x4 x4 = xpair((W2).x, (W2).y, adj);                                 \
            f32x4 x5 = xpair((W2).z, (W2).w, adj);                                 \
            f32x4 x6 = xpair((W3).x, (W3).y, adj);                                 \
            f32x4 x7 = xpair((W3).z, (W3).w, adj);                                 \
            f32x4 p0 = vmin4(d0 * x0, 448.f), p1 = vmin4(d1 * x1, 448.f);          \
            f32x4 p2 = vmin4(d2 * x2, 448.f), p3 = vmin4(d3 * x3, 448.f);          \
            f32x4 p4 = vmin4(d4 * x4, 448.f), p5 = vmin4(d5 * x5, 448.f);          \
            f32x4 p6 = vmin4(d6 * x6, 448.f), p7 = vmin4(d7 * x7, 448.f);          \
            Aq[0] = pk4(p0.x, p1.x, p2.x, p3.x);                                   \
            Aq[1] = pk4(p4.x, p5.x, p6.x, p7.x);                                   \
            Aq[2] = pk4(p0.y, p1.y, p2.y, p3.y);                                   \
            Aq[3] = pk4(p4.y, p5.y, p6.y, p7.y);                                   \
            Aq[4] = pk4(p0.z, p1.z, p2.z, p3.z);                                   \
            Aq[5] = pk4(p4.z, p5.z, p6.z, p7.z);                                   \
            Aq[6] = pk4(p0.w, p1.w, p2.w, p3.w);                                   \
            Aq[7] = pk4(p4.w, p5.w, p6.w, p7.w);                                   \
        }

        LOADT(wA0, wA1, wA2, wA3, 0)
        LOADT(wB0, wB1, wB2, wB3, 1)
        int i = 0;
        for (;;) {
            STEPT(wA0, wA1, wA2, wA3)
            if (++i == steps) break;
            LOADT(wA0, wA1, wA2, wA3, i + 1)
            STEPT(wB0, wB1, wB2, wB3)
            if (++i == steps) break;
            LOADT(wB0, wB1, wB2, wB3, i + 1)
        }
#undef STEPT
#undef MFS
#undef LOADT
    }

    // ---- seam + scale to ws (byte order identical to r12/r13: slot s holds q[k(s)]) ----
    if (m == 0) {
        i32x4* sp = (i32x4*)(ws + (dir ? WS_QB : WS_QF) + b * L + 32 * g);
        sp[0] = (i32x4){Aq[0], Aq[1], Aq[2], Aq[3]};
        sp[1] = (i32x4){Aq[4], Aq[5], Aq[6], Aq[7]};
    }
    if (lane == 0) {
        ((float*)(ws + (dir ? WS_SB : WS_SF)))[b] = S_base + 0.69314718f * (float)Se;
        if (dir == 0) ((int*)(ws + WS_N))[b] = n;
    }
}

// Fallback (ws too small for the table): verbatim r14 path — known-passing.
__global__ __launch_bounds__(64, 1) void k_scan_f32(
        const float* __restrict__ emit, const int* __restrict__ labels,
        const void* __restrict__ masks, const float* __restrict__ T,
        unsigned char* __restrict__ ws, float* __restrict__ out) {
    const int bid  = blockIdx.x;
    const int lane = threadIdx.x;

    if (bid >= 2 * BATCH) { gold_block(emit, labels, masks, T, out, bid - 2 * BATCH, lane); return; }

    const int b   = bid & (BATCH - 1);
    const int dir = bid >> 8;
    const int g = lane >> 4, m = lane & 15;

    const int len = compute_len(masks, b, lane);
    const int n  = len - 1;
    const int kf = n / 2;
    const int nB = n - kf - 1;
    const int steps = dir ? (nB > 0 ? nB : 0) : kf;
    if (dir == 1 && n < 1) return;

    i32x8 Af[8];
    #pragma unroll
    for (int t = 0; t < 8; ++t) {
        #pragma unroll
        for (int d = 0; d < 8; ++d) {
            float v[4];
            #pragma unroll
            for (int y = 0; y < 4; ++y) {
                int sl = 4 * d + y;
                int k  = 16 * (sl & 7) + 4 * g + (sl >> 3);
                int idx = dir ? ((16 * t + m) * L + k) : (k * L + 16 * t + m);
                v[y] = __expf(T[idx]);
            }
            Af[t][d] = pk4(v[0], v[1], v[2], v[3]);
        }
    }

    float S_base;
    i32x8 Aq;
    {
        f32x4 fv[8];
        const float* e0 = emit + (dir ? ((size_t)n * BATCH + b) * L : (size_t)b * L);
        #pragma unroll
        for (int t = 0; t < 8; ++t) {
            int k0 = 16 * t + 4 * g;
            f32x4 ev4 = *(const f32x4*)(e0 + k0);
            f32x4 tv;
            if (dir == 0) {
                tv = *(const f32x4*)(T + START_ID * L + k0);
            } else {
                tv.x = T[(k0 + 0) * L + PAD_ID];
                tv.y = T[(k0 + 1) * L + PAD_ID];
                tv.z = T[(k0 + 2) * L + PAD_ID];
                tv.w = T[(k0 + 3) * L + PAD_ID];
            }
            fv[t] = ev4 + tv;
        }
        float mx = -1e30f;
        #pragma unroll
        for (int t = 0; t < 8; ++t)
            mx = fmaxf(mx, fmaxf(fmaxf(fv[t].x, fv[t].y), fmaxf(fv[t].z, fv[t].w)));
        mx = fmaxf(mx, __shfl_xor(mx, 16, 64));
        mx = fmaxf(mx, __shfl_xor(mx, 32, 64));
        S_base = mx;
        f32x4 pv[8];
        #pragma unroll
        for (int t = 0; t < 8; ++t) pv[t] = vexp4(fv[t] - S_base);
        Aq[0] = pk4(pv[0].x, pv[1].x, pv[2].x, pv[3].x);
        Aq[1] = pk4(pv[4].x, pv[5].x, pv[6].x, pv[7].x);
        Aq[2] = pk4(pv[0].y, pv[1].y, pv[2].y, pv[3].y);
        Aq[3] = pk4(pv[4].y, pv[5].y, pv[6].y, pv[7].y);
        Aq[4] = pk4(pv[0].z, pv[1].z, pv[2].z, pv[3].z);
        Aq[5] = pk4(pv[4].z, pv[5].z, pv[6].z, pv[7].z);
        Aq[6] = pk4(pv[0].w, pv[1].w, pv[2].w, pv[3].w);
        Aq[7] = pk4(pv[4].w, pv[5].w, pv[6].w, pv[7].w);
    }

    int Se = 0;
    const f32x4 z = {0.f, 0.f, 0.f, 0.f};

    if (steps > 0) {
        auto ldrow8 = [&](int idx, f32x4* dst) {
            int ii  = idx < steps ? idx : steps - 1;
            int row = dir ? (n - 1 - ii) : (1 + ii);
            const float* ep = emit + ((size_t)row * BATCH + b) * L + 4 * g;
            #pragma unroll
            for (int t = 0; t < 8; ++t) dst[t] = *(const f32x4*)(ep + 16 * t);
        };
        f32x4 ea[8], eb[8], ec[8];
        ldrow8(0, ea); ldrow8(1, eb); ldrow8(2, ec);
        int i = 0;

#define MFS(AT) __builtin_amdgcn_mfma_scale_f32_16x16x128_f8f6f4((AT), Aq, z, 0, 0, 0, 127, 0, 127)
#define STEP(EB)                                                                   \
        {                                                                          \
            f32x4 d0 = MFS(Af[0]), d1 = MFS(Af[1]), d2 = MFS(Af[2]), d3 = MFS(Af[3]); \
            f32x4 d4 = MFS(Af[4]), d5 = MFS(Af[5]), d6 = MFS(Af[6]), d7 = MFS(Af[7]); \
            f32x4 x0 = vexp4(EB[0]), x1 = vexp4(EB[1]), x2 = vexp4(EB[2]),         \
                  x3 = vexp4(EB[3]), x4 = vexp4(EB[4]), x5 = vexp4(EB[5]),         \
                  x6 = vexp4(EB[6]), x7 = vexp4(EB[7]);                            \
            u32x4 qlo = {(unsigned)Aq[0], (unsigned)Aq[1],                         \
                         (unsigned)Aq[2], (unsigned)Aq[3]};                        \
            u32x4 qhi = {(unsigned)Aq[4], (unsigned)Aq[5],                         \
                         (unsigned)Aq[6], (unsigned)Aq[7]};                        \
            unsigned int qm = bmax8(qlo, qhi);                                     \
            {                                                                      \
                unsigned int q2 = (unsigned int)__shfl_xor((int)qm, 16, 64);       \
                qm = qm > q2 ? qm : q2;                                            \
                q2 = (unsigned int)__shfl_xor((int)qm, 32, 64);                    \
                qm = qm > q2 ? qm : q2;                                            \
            }                                                                      \
            int e7 = (int)(qm >> 3) - 7;                                           \
            Se += e7;                                                              \
            float kk = __builtin_bit_cast(float, (unsigned int)(127 - e7) << 23);  \
            x0 *= kk; x1 *= kk; x2 *= kk; x3 *= kk;                                \
            x4 *= kk; x5 *= kk; x6 *= kk; x7 *= kk;                                \
            f32x4 p0 = vmin4(d0 * x0, 448.f), p1 = vmin4(d1 * x1, 448.f);          \
            f32x4 p2 = vmin4(d2 * x2, 448.f), p3 = vmin4(d3 * x3, 448.f);          \
            f32x4 p4 = vmin4(d4 * x4, 448.f), p5 = vmin4(d5 * x5, 448.f);          \
            f32x4 p6 = vmin4(d6 * x6, 448.f), p7 = vmin4(d7 * x7, 448.f);          \
            Aq[0] = pk4(p0.x, p1.x, p2.x, p3.x);                                   \
            Aq[1] = pk4(p4.x, p5.x, p6.x, p7.x);                                   \
            Aq[2] = pk4(p0.y, p1.y, p2.y, p3.y);                                   \
            Aq[3] = pk4(p4.y, p5.y, p6.y, p7.y);                                   \
            Aq[4] = pk4(p0.z, p1.z, p2.z, p3.z);                                   \
            Aq[5] = pk4(p4.z, p5.z, p6.z, p7.z);                                   \
            Aq[6] = pk4(p0.w, p1.w, p2.w, p3.w);                                   \
            Aq[7] = pk4(p4.w, p5.w, p6.w, p7.w);                                   \
        }

        for (;;) {
            STEP(ea); if (++i == steps) break; ldrow8(i + 2, ea);
            STEP(eb); if (++i == steps) break; ldrow8(i + 2, eb);
            STEP(ec); if (++i == steps) break; ldrow8(i + 2, ec);
        }
#undef STEP
#undef MFS
    }

    if (m == 0) {
        i32x4* sp = (i32x4*)(ws + (dir ? WS_QB : WS_QF) + b * L + 32 * g);
        sp[0] = (i32x4){Aq[0], Aq[1], Aq[2], Aq[3]};
        sp[1] = (i32x4){Aq[4], Aq[5], Aq[6], Aq[7]};
    }
    if (lane == 0) {
        ((float*)(ws + (dir ? WS_SB : WS_SF)))[b] = S_base + 0.69314718f * (float)Se;
        if (dir == 0) ((int*)(ws + WS_N))[b] = n;
    }
}

// Exact-f32 join: enc_b = Sf + Sb + log(q_kf^T E u_{kf+1})  (n=0: Sf + log(q0.expTpad))
__global__ __launch_bounds__(64, 1) void k_join(
        const float* __restrict__ T, const unsigned char* __restrict__ ws,
        float* __restrict__ out) {
    const int b = blockIdx.x;
    const int lane = threadIdx.x;
    __shared__ float qsh[L], ush[L];

    const int n = ((const int*)(ws + WS_N))[b];
    #pragma unroll
    for (int k = 0; k < 2; ++k) {
        int s = lane + 64 * k;
        int j = 16 * (s & 7) + (s >> 3);
        qsh[j] = fp8dec(ws[WS_QF + b * L + s]);
        ush[j] = fp8dec(ws[WS_QB + b * L + s]);
    }
    __syncthreads();

    float ev = 0.f;
    if (n >= 1) {
        #pragma unroll
        for (int k = 0; k < 2; ++k) {
            int j = lane + 64 * k;
            float v0 = 0.f, v1 = 0.f, v2 = 0.f, v3 = 0.f;
            #pragma unroll 8
            for (int i = 0; i < L; i += 4) {
                v0 = fmaf(qsh[i + 0], __expf(T[(i + 0) * L + j]), v0);
                v1 = fmaf(qsh[i + 1], __expf(T[(i + 1) * L + j]), v1);
                v2 = fmaf(qsh[i + 2], __expf(T[(i + 2) * L + j]), v2);
                v3 = fmaf(qsh[i + 3], __expf(T[(i + 3) * L + j]), v3);
            }
            ev += ((v0 + v1) + (v2 + v3)) * ush[j];
        }
    } else {
        #pragma unroll
        for (int k = 0; k < 2; ++k) {
            int j = lane + 64 * k;
            ev += qsh[j] * __expf(T[j * L + PAD_ID]);
        }
    }
    #pragma unroll
    for (int off = 32; off; off >>= 1) ev += __shfl_xor(ev, off, 64);

    if (lane == 0) {
        float Sf = ((const float*)(ws + WS_SF))[b];
        float Sb = (n >= 1) ? ((const float*)(ws + WS_SB))[b] : 0.f;
        float enc = Sf + Sb + __logf(fmaxf(ev, 1e-35f));
        atomicAdd(out, sane(enc, -1e30f, 1e30f));
    }
}

extern "C" void kernel_launch(void* const* d_in, const int* in_sizes, int n_in,
                              void* d_out, int out_size, void* d_ws, size_t ws_size,
                              hipStream_t stream) {
    const float* emit   = (const float*)d_in[0];
    const int*   labels = (const int*)d_in[1];
    const void*  masks  = d_in[2];
    const float* T      = (const float*)d_in[3];
    float* out = (float*)d_out;
    unsigned char* ws = (unsigned char*)d_ws;

    hipMemsetAsync(d_out, 0, sizeof(float), stream);
    if (ws_size >= (size_t)WS_TAB + TAB_BYTES) {
        k_pre<<<dim3(4096), dim3(256), 0, stream>>>(emit, ws + WS_TAB);
        k_scan_tab<<<dim3(3 * BATCH), dim3(64), 0, stream>>>(emit, labels, masks, T, ws, out);
    } else {
        k_scan_f32<<<dim3(3 * BATCH), dim3(64), 0, stream>>>(emit, labels, masks, T, ws, out);
    }
    k_join<<<dim3(BATCH), dim3(64), 0, stream>>>(T, ws, out);
}